// Round 6
// baseline (131.405 us; speedup 1.0000x reference)
//
#include <hip/hip_runtime.h>
#include <math.h>

#define NPTS 32768
#define NIMG 32          // B*C = 8*4
#define CAPP 192         // per-tile point capacity (mean ~85, max ~126)
#define CAPC 57          // per-cell entry capacity (mean ~18, max ~46); odd -> bank-conflict-free
#define SCALE ((float)(256.0 / (2.0 * M_PI)))

// ---------- I0 Bessel (double, for setup) ----------
static __device__ __forceinline__ double bessel_i0d(double x) {
    double hx2 = 0.25 * x * x;
    double t = 1.0, s = 1.0;
#pragma unroll
    for (int m = 1; m <= 40; ++m) {
        t *= hx2 * (1.0 / ((double)m * (double)m));
        s += t;
    }
    return s;
}

// ---------- I0 Bessel (float) ----------
static __device__ __forceinline__ float bessel_i0f(float x) {
    float hx2 = 0.25f * x * x;
    float t = 1.0f, s = 1.0f;
#pragma unroll
    for (int m = 1; m <= 30; ++m) {
        t *= hx2 * (1.0f / ((float)m * (float)m));
        s += t;
    }
    return s;
}

// ---------- S[d] = sum_{x<128} ax[x] * exp(2*pi*i*x*d/256), table-based ----------
__global__ void k_setup_S(float2* __restrict__ S) {
    __shared__ double ere[256], eim[256];
    __shared__ float ax[128];
    int t = threadIdx.x;              // 0..255
    double ang = (double)t * (2.0 * M_PI / 256.0);
    ere[t] = cos(ang);                // one trig pair per thread
    eim[t] = sin(ang);
    if (t < 128) {
        double i0a = bessel_i0d(14.04);
        double om = ((double)t - 63.5) * (1.0 / 256.0);
        double pj = M_PI * 6.0 * om;
        double tt = sqrt(14.04 * 14.04 - pj * pj);   // always real here
        double kbft = 6.0 * (sinh(tt) / tt) / i0a;
        ax[t] = (float)(1.0 / kbft);                 // apodization 1D
    }
    __syncthreads();
    double re = 0.0, im = 0.0;
    for (int x = 0; x < 128; ++x) {
        int ph = (x * t) & 255;                      // exact phase reduction
        re += (double)ax[x] * ere[ph];
        im += (double)ax[x] * eim[ph];
    }
    S[t] = make_float2((float)re, (float)im);
}

// ---------- fused per-point: 1D weights + 8x8 tile binning ----------
__global__ void k_prep(const float* __restrict__ coords, float* __restrict__ wxy,
                       unsigned* __restrict__ tileCount,   // [1024]
                       unsigned* __restrict__ bins) {      // [1024][CAPP]
    int k = blockIdx.x * blockDim.x + threadIdx.x;
    if (k >= NPTS) return;
    const float inv_i0a = 1.0f / bessel_i0f(14.04f);  // constant-folds
    float gmx = coords[2 * k]     * SCALE;
    float gmy = coords[2 * k + 1] * SCALE;
    float bxf = floorf(gmx - 3.0f), byf = floorf(gmy - 3.0f);
#pragma unroll
    for (int j = 0; j < 6; ++j) {
        float ux = gmx - (bxf + (float)(j + 1));
        float rx = ux * (1.0f / 3.0f);
        float argx = 1.0f - rx * rx;
        wxy[k * 12 + j] = (argx > 0.0f) ? bessel_i0f(14.04f * sqrtf(argx)) * inv_i0a : 0.0f;
        float uy = gmy - (byf + (float)(j + 1));
        float ry = uy * (1.0f / 3.0f);
        float argy = 1.0f - ry * ry;
        wxy[k * 12 + 6 + j] = (argy > 0.0f) ? bessel_i0f(14.04f * sqrtf(argy)) * inv_i0a : 0.0f;
    }
    int x0 = (((int)bxf) + 1 + 512) & 255;
    int y0 = (((int)byf) + 1 + 512) & 255;
    int tx0 = x0 >> 3, tx1 = ((x0 + 5) & 255) >> 3;
    int ty0 = y0 >> 3, ty1 = ((y0 + 5) & 255) >> 3;
    int nx = (tx1 == tx0) ? 1 : 2;
    int ny = (ty1 == ty0) ? 1 : 2;
    int txs[2] = {tx0, tx1}, tys[2] = {ty0, ty1};
    for (int i = 0; i < nx; ++i)
        for (int j = 0; j < ny; ++j) {
            int tile = txs[i] * 32 + tys[j];
            unsigned pos = atomicAdd(&tileCount[tile], 1u);
            if (pos < CAPP) bins[tile * CAPP + pos] = (unsigned)k;
        }
}

// ---------- transpose values [img][k] -> vt [k][img] ----------
__global__ void k_transpose(const float* __restrict__ values, float* __restrict__ vt) {
    __shared__ float tile[32][257];
    int kbase = blockIdx.x * 256;
    int t = threadIdx.x;
    for (int img = 0; img < 32; ++img)
        tile[img][t] = values[img * NPTS + kbase + t];
    __syncthreads();
    int img = t & 31;
    int k0 = t >> 5;                   // 0..7
    for (int r = 0; r < 32; ++r) {
        int kl = k0 + r * 8;           // 0..255
        vt[(kbase + kl) * 32 + img] = tile[img][kl];
    }
}

// ---------- tile gather: per-cell LDS lists + register accumulation ----------
__global__ __launch_bounds__(256) void k_gather_tile(
        const float* __restrict__ coords, const float* __restrict__ wxy,
        const float* __restrict__ vt,
        const unsigned* __restrict__ tileCount, const unsigned* __restrict__ bins,
        float* __restrict__ grid) {
    __shared__ unsigned cnt[64];
    __shared__ unsigned lists[64 * CAPC];   // entry = (k:15 << 16) | (w:16)
    __shared__ unsigned kk[CAPP];
    __shared__ int xx[CAPP], yy[CAPP];
    int tile = blockIdx.x;                  // 0..1023
    int TX = tile >> 5, TY = tile & 31;
    int t = threadIdx.x;
    if (t < 64) cnt[t] = 0u;
    unsigned n = tileCount[tile];
    if (n > CAPP) n = CAPP;
    for (int p = t; p < (int)n; p += 256) {
        unsigned k = bins[tile * CAPP + p];
        kk[p] = k;
        float gmx = coords[2 * k]     * SCALE;
        float gmy = coords[2 * k + 1] * SCALE;
        xx[p] = ((int)floorf(gmx - 3.0f)) + 1 + 512;   // keep positive; &255 later
        yy[p] = ((int)floorf(gmy - 3.0f)) + 1 + 512;
    }
    __syncthreads();
    // stage A: build per-cell entry lists
    int total = (int)n * 36;
    for (int idx = t; idx < total; idx += 256) {
        int pi = idx / 36;
        int tap = idx - pi * 36;
        int jx = tap / 6, jy = tap - jx * 6;
        int cx = (xx[pi] + jx) & 255;
        int cy = (yy[pi] + jy) & 255;
        if ((cx >> 3) == TX && (cy >> 3) == TY) {
            unsigned k = kk[pi];
            float w = wxy[k * 12 + jx] * wxy[k * 12 + 6 + jy];
            unsigned q = (unsigned)(w * 65535.0f + 0.5f);
            if (q > 65535u) q = 65535u;
            int cl = ((cx & 7) << 3) | (cy & 7);
            unsigned pos = atomicAdd(&cnt[cl], 1u);    // native u32 LDS atomic
            if (pos < CAPC) lists[cl * CAPC + pos] = (k << 16) | q;
        }
    }
    __syncthreads();
    // stage B: thread owns (cell c, 8 images); pure register gather
    int c = t >> 2;
    int ib = (t & 3) * 8;
    unsigned nc = cnt[c];
    if (nc > CAPC) nc = CAPC;
    float acc0 = 0, acc1 = 0, acc2 = 0, acc3 = 0, acc4 = 0, acc5 = 0, acc6 = 0, acc7 = 0;
    for (unsigned e = 0; e < nc; ++e) {
        unsigned en = lists[c * CAPC + e];             // broadcast within quad
        float w = (float)(en & 0xFFFFu) * (1.0f / 65535.0f);
        const float* vp = &vt[(en >> 16) * 32 + ib];
        float4 va = *(const float4*)vp;
        float4 vb = *(const float4*)(vp + 4);
        acc0 += w * va.x; acc1 += w * va.y; acc2 += w * va.z; acc3 += w * va.w;
        acc4 += w * vb.x; acc5 += w * vb.y; acc6 += w * vb.z; acc7 += w * vb.w;
    }
    int gc = (((TX << 3) + (c >> 3)) << 8) | ((TY << 3) + (c & 7));
    float accs[8] = {acc0, acc1, acc2, acc3, acc4, acc5, acc6, acc7};
#pragma unroll
    for (int j = 0; j < 8; ++j)
        grid[(ib + j) * 65536 + gc] = accs[j];
}

// ---------- fused mm, register-blocked: band of 8 p-rows per block ----------
// stage 1: T1[p][v] = sum_u S[(u-2p)&255] * G[img][u][v]   (thread: 4 cols x 2 rows)
// stage 2: F[p][q] = sum_v T1[p][v] * S[(v-2q)&255]        (thread: 2 rows x 2 q)
__global__ __launch_bounds__(256) void k_mm(const float* __restrict__ grid,
                                            const float2* __restrict__ S,
                                            float* __restrict__ out) {
    __shared__ float2 ssh[256];            // S (stage 1 broadcast reads)
    __shared__ float4 SeSo[128];           // (S[2m], S[2m+1]) packed (stage 2 lane reads)
    __shared__ float2 trow[8][256];        // 8 T1 rows of this band (16 KB)
    int t = threadIdx.x;
    int p0 = blockIdx.x * 8;               // p-band
    int img = blockIdx.y;
    ssh[t] = S[t];
    if (t < 128) SeSo[t] = ((const float4*)S)[t];
    __syncthreads();

    // ---- stage 1 ----
    int cg = t & 63;                       // columns 4*cg .. 4*cg+3 (lane-stride-1 -> coalesced)
    int rg = t >> 6;                       // wave index 0..3 (uniform per wave)
    int r0 = p0 + rg * 2;                  // two rows r0, r0+1
    const float* g = grid + img * 65536 + cg * 4;
    float4 re0 = {0,0,0,0}, im0 = {0,0,0,0}, re1 = {0,0,0,0}, im1 = {0,0,0,0};
#pragma unroll 2
    for (int u = 0; u < 256; ++u) {
        float4 gv = *(const float4*)(g + (u << 8));
        float2 s0 = ssh[(u - 2 * r0) & 255];        // wave-uniform -> broadcast
        float2 s1 = ssh[(u - 2 * r0 - 2) & 255];
        re0.x += s0.x * gv.x; re0.y += s0.x * gv.y; re0.z += s0.x * gv.z; re0.w += s0.x * gv.w;
        im0.x += s0.y * gv.x; im0.y += s0.y * gv.y; im0.z += s0.y * gv.z; im0.w += s0.y * gv.w;
        re1.x += s1.x * gv.x; re1.y += s1.x * gv.y; re1.z += s1.x * gv.z; re1.w += s1.x * gv.w;
        im1.x += s1.y * gv.x; im1.y += s1.y * gv.y; im1.z += s1.y * gv.z; im1.w += s1.y * gv.w;
    }
    {
        float4* tp0 = (float4*)&trow[rg * 2][cg * 4];
        tp0[0] = make_float4(re0.x, im0.x, re0.y, im0.y);
        tp0[1] = make_float4(re0.z, im0.z, re0.w, im0.w);
        float4* tp1 = (float4*)&trow[rg * 2 + 1][cg * 4];
        tp1[0] = make_float4(re1.x, im1.x, re1.y, im1.y);
        tp1[1] = make_float4(re1.z, im1.z, re1.w, im1.w);
    }
    __syncthreads();

    // ---- stage 2 ----
    int q0 = t & 63;                       // q in {q0, q0+64}
    const float2* tr0 = trow[rg * 2];
    const float2* tr1 = trow[rg * 2 + 1];
    float rr00 = 0, ii00 = 0, rr01 = 0, ii01 = 0;
    float rr10 = 0, ii10 = 0, rr11 = 0, ii11 = 0;
#pragma unroll 2
    for (int h = 0; h < 128; ++h) {
        int m0 = (h - q0) & 127;
        float4 sa = SeSo[m0];              // lane-stride-1
        float4 sb = SeSo[m0 ^ 64];         // = index for q0+64
        float4 ta = *(const float4*)&tr0[2 * h];   // broadcast (v=2h, 2h+1)
        float4 tb = *(const float4*)&tr1[2 * h];
        rr00 += ta.x * sa.x - ta.y * sa.y + ta.z * sa.z - ta.w * sa.w;
        ii00 += ta.x * sa.y + ta.y * sa.x + ta.z * sa.w + ta.w * sa.z;
        rr01 += ta.x * sb.x - ta.y * sb.y + ta.z * sb.z - ta.w * sb.w;
        ii01 += ta.x * sb.y + ta.y * sb.x + ta.z * sb.w + ta.w * sb.z;
        rr10 += tb.x * sa.x - tb.y * sa.y + tb.z * sa.z - tb.w * sa.w;
        ii10 += tb.x * sa.y + tb.y * sa.x + tb.z * sa.w + tb.w * sa.z;
        rr11 += tb.x * sb.x - tb.y * sb.y + tb.z * sb.z - tb.w * sb.w;
        ii11 += tb.x * sb.y + tb.y * sb.x + tb.z * sb.w + tb.w * sb.z;
    }
    int b = img >> 2, c = img & 3;
    int obase = ((b ^ 4) * 4 + (c ^ 2)) * 128;
    int pa = p0 + rg * 2, pb = pa + 1;
    out[((obase + (pa ^ 64)) << 7) + ((q0) ^ 64)]      = sqrtf(rr00 * rr00 + ii00 * ii00);
    out[((obase + (pa ^ 64)) << 7) + ((q0 + 64) ^ 64)] = sqrtf(rr01 * rr01 + ii01 * ii01);
    out[((obase + (pb ^ 64)) << 7) + ((q0) ^ 64)]      = sqrtf(rr10 * rr10 + ii10 * ii10);
    out[((obase + (pb ^ 64)) << 7) + ((q0 + 64) ^ 64)] = sqrtf(rr11 * rr11 + ii11 * ii11);
}

extern "C" void kernel_launch(void* const* d_in, const int* in_sizes, int n_in,
                              void* d_out, int out_size, void* d_ws, size_t ws_size,
                              hipStream_t stream) {
    const float* values = (const float*)d_in[0];   // [8,4,32768] f32
    const float* coords = (const float*)d_in[1];   // [32768,2] f32

    char* ws = (char*)d_ws;
    // layout (peak ~14.7 MB):
    float2*   S         = (float2*)(ws + 0);             // 2 KB
    unsigned* tileCount = (unsigned*)(ws + 8192);        // 4 KB   [1024]
    float*    wxy       = (float*)(ws + 12288);          // 1.5 MB [32768*12]
    unsigned* bins      = (unsigned*)(ws + 1585152);     // 768 KB [1024*CAPP]
    float*    grid      = (float*)(ws + 2371584);        // 8 MB   [32][256][256]
    float*    vt        = (float*)(ws + 10760192);       // 4 MB   [32768][32]

    hipMemsetAsync(tileCount, 0, 1024 * sizeof(unsigned), stream);

    k_setup_S<<<1, 256, 0, stream>>>(S);
    k_prep<<<(NPTS + 255) / 256, 256, 0, stream>>>(coords, wxy, tileCount, bins);
    k_transpose<<<NPTS / 256, 256, 0, stream>>>(values, vt);
    k_gather_tile<<<1024, 256, 0, stream>>>(coords, wxy, vt, tileCount, bins, grid);
    k_mm<<<dim3(16, 32), 256, 0, stream>>>(grid, S, (float*)d_out);
}

// Round 7
// 107.948 us; speedup vs baseline: 1.2173x; 1.2173x over previous
//
#include <hip/hip_runtime.h>
#include <math.h>

#define NPTS 32768
#define NIMG 32          // B*C = 8*4
#define CAPP 192         // per-tile point capacity (mean ~85, max ~126)
#define CAPC 57          // per-cell entry capacity (mean ~18, max ~46); odd -> bank-conflict-free
#define SCALE ((float)(256.0 / (2.0 * M_PI)))

// ---------- I0 Bessel (double, for setup) ----------
static __device__ __forceinline__ double bessel_i0d(double x) {
    double hx2 = 0.25 * x * x;
    double t = 1.0, s = 1.0;
#pragma unroll
    for (int m = 1; m <= 40; ++m) {
        t *= hx2 * (1.0 / ((double)m * (double)m));
        s += t;
    }
    return s;
}

// ---------- I0 Bessel (float) ----------
static __device__ __forceinline__ float bessel_i0f(float x) {
    float hx2 = 0.25f * x * x;
    float t = 1.0f, s = 1.0f;
#pragma unroll
    for (int m = 1; m <= 30; ++m) {
        t *= hx2 * (1.0f / ((float)m * (float)m));
        s += t;
    }
    return s;
}

// ---------- S[d] = sum_{x<128} ax[x] * exp(2*pi*i*x*d/256), table-based ----------
__global__ void k_setup_S(float2* __restrict__ S) {
    __shared__ double ere[256], eim[256];
    __shared__ float ax[128];
    int t = threadIdx.x;              // 0..255
    double ang = (double)t * (2.0 * M_PI / 256.0);
    ere[t] = cos(ang);                // one trig pair per thread
    eim[t] = sin(ang);
    if (t < 128) {
        double i0a = bessel_i0d(14.04);
        double om = ((double)t - 63.5) * (1.0 / 256.0);
        double pj = M_PI * 6.0 * om;
        double tt = sqrt(14.04 * 14.04 - pj * pj);   // always real here
        double kbft = 6.0 * (sinh(tt) / tt) / i0a;
        ax[t] = (float)(1.0 / kbft);                 // apodization 1D
    }
    __syncthreads();
    double re = 0.0, im = 0.0;
    for (int x = 0; x < 128; ++x) {
        int ph = (x * t) & 255;                      // exact phase reduction
        re += (double)ax[x] * ere[ph];
        im += (double)ax[x] * eim[ph];
    }
    S[t] = make_float2((float)re, (float)im);
}

// ---------- fused per-point: 1D weights + 8x8 tile binning ----------
__global__ void k_prep(const float* __restrict__ coords, float* __restrict__ wxy,
                       unsigned* __restrict__ tileCount,   // [1024]
                       unsigned* __restrict__ bins) {      // [1024][CAPP]
    int k = blockIdx.x * blockDim.x + threadIdx.x;
    if (k >= NPTS) return;
    const float inv_i0a = 1.0f / bessel_i0f(14.04f);  // constant-folds
    float gmx = coords[2 * k]     * SCALE;
    float gmy = coords[2 * k + 1] * SCALE;
    float bxf = floorf(gmx - 3.0f), byf = floorf(gmy - 3.0f);
#pragma unroll
    for (int j = 0; j < 6; ++j) {
        float ux = gmx - (bxf + (float)(j + 1));
        float rx = ux * (1.0f / 3.0f);
        float argx = 1.0f - rx * rx;
        wxy[k * 12 + j] = (argx > 0.0f) ? bessel_i0f(14.04f * sqrtf(argx)) * inv_i0a : 0.0f;
        float uy = gmy - (byf + (float)(j + 1));
        float ry = uy * (1.0f / 3.0f);
        float argy = 1.0f - ry * ry;
        wxy[k * 12 + 6 + j] = (argy > 0.0f) ? bessel_i0f(14.04f * sqrtf(argy)) * inv_i0a : 0.0f;
    }
    int x0 = (((int)bxf) + 1 + 512) & 255;
    int y0 = (((int)byf) + 1 + 512) & 255;
    int tx0 = x0 >> 3, tx1 = ((x0 + 5) & 255) >> 3;
    int ty0 = y0 >> 3, ty1 = ((y0 + 5) & 255) >> 3;
    int nx = (tx1 == tx0) ? 1 : 2;
    int ny = (ty1 == ty0) ? 1 : 2;
    int txs[2] = {tx0, tx1}, tys[2] = {ty0, ty1};
    for (int i = 0; i < nx; ++i)
        for (int j = 0; j < ny; ++j) {
            int tile = txs[i] * 32 + tys[j];
            unsigned pos = atomicAdd(&tileCount[tile], 1u);
            if (pos < CAPP) bins[tile * CAPP + pos] = (unsigned)k;
        }
}

// ---------- transpose values [img][k] -> vt [k][img] ----------
__global__ void k_transpose(const float* __restrict__ values, float* __restrict__ vt) {
    __shared__ float tile[32][257];
    int kbase = blockIdx.x * 256;
    int t = threadIdx.x;
    for (int img = 0; img < 32; ++img)
        tile[img][t] = values[img * NPTS + kbase + t];
    __syncthreads();
    int img = t & 31;
    int k0 = t >> 5;                   // 0..7
    for (int r = 0; r < 32; ++r) {
        int kl = k0 + r * 8;           // 0..255
        vt[(kbase + kl) * 32 + img] = tile[img][kl];
    }
}

// ---------- tile gather: per-cell LDS lists + register accumulation ----------
__global__ __launch_bounds__(256) void k_gather_tile(
        const float* __restrict__ coords, const float* __restrict__ wxy,
        const float* __restrict__ vt,
        const unsigned* __restrict__ tileCount, const unsigned* __restrict__ bins,
        float* __restrict__ grid) {
    __shared__ unsigned cnt[64];
    __shared__ unsigned lists[64 * CAPC];   // entry = (k:15 << 16) | (w:16)
    __shared__ unsigned kk[CAPP];
    __shared__ int xx[CAPP], yy[CAPP];
    __shared__ float wsh[CAPP * 12];        // staged per-point 1D weights (9 KB)
    int tile = blockIdx.x;                  // 0..1023
    int TX = tile >> 5, TY = tile & 31;
    int t = threadIdx.x;
    if (t < 64) cnt[t] = 0u;
    unsigned n = tileCount[tile];
    if (n > CAPP) n = CAPP;
    for (int p = t; p < (int)n; p += 256) {
        unsigned k = bins[tile * CAPP + p];
        kk[p] = k;
        float gmx = coords[2 * k]     * SCALE;
        float gmy = coords[2 * k + 1] * SCALE;
        xx[p] = ((int)floorf(gmx - 3.0f)) + 1 + 512;   // keep positive; &255 later
        yy[p] = ((int)floorf(gmy - 3.0f)) + 1 + 512;
        const float4* wp = (const float4*)&wxy[k * 12];  // 48B, 16-aligned
        *(float4*)&wsh[p * 12 + 0] = wp[0];
        *(float4*)&wsh[p * 12 + 4] = wp[1];
        *(float4*)&wsh[p * 12 + 8] = wp[2];
    }
    __syncthreads();
    // stage A: build per-cell entry lists (weights from LDS)
    int total = (int)n * 36;
    for (int idx = t; idx < total; idx += 256) {
        int pi = idx / 36;
        int tap = idx - pi * 36;
        int jx = tap / 6, jy = tap - jx * 6;
        int cx = (xx[pi] + jx) & 255;
        int cy = (yy[pi] + jy) & 255;
        if ((cx >> 3) == TX && (cy >> 3) == TY) {
            float w = wsh[pi * 12 + jx] * wsh[pi * 12 + 6 + jy];
            unsigned q = (unsigned)(w * 65535.0f + 0.5f);
            if (q > 65535u) q = 65535u;
            int cl = ((cx & 7) << 3) | (cy & 7);
            unsigned pos = atomicAdd(&cnt[cl], 1u);    // native u32 LDS atomic
            if (pos < CAPC) lists[cl * CAPC + pos] = (kk[pi] << 16) | q;
        }
    }
    __syncthreads();
    // stage B: thread owns (cell c, 8 images); pure register gather
    int c = t >> 2;
    int ib = (t & 3) * 8;
    unsigned nc = cnt[c];
    if (nc > CAPC) nc = CAPC;
    float acc0 = 0, acc1 = 0, acc2 = 0, acc3 = 0, acc4 = 0, acc5 = 0, acc6 = 0, acc7 = 0;
    for (unsigned e = 0; e < nc; ++e) {
        unsigned en = lists[c * CAPC + e];             // broadcast within quad
        float w = (float)(en & 0xFFFFu) * (1.0f / 65535.0f);
        const float* vp = &vt[(en >> 16) * 32 + ib];
        float4 va = *(const float4*)vp;
        float4 vb = *(const float4*)(vp + 4);
        acc0 += w * va.x; acc1 += w * va.y; acc2 += w * va.z; acc3 += w * va.w;
        acc4 += w * vb.x; acc5 += w * vb.y; acc6 += w * vb.z; acc7 += w * vb.w;
    }
    int gc = (((TX << 3) + (c >> 3)) << 8) | ((TY << 3) + (c & 7));
    float accs[8] = {acc0, acc1, acc2, acc3, acc4, acc5, acc6, acc7};
#pragma unroll
    for (int j = 0; j < 8; ++j)
        grid[(ib + j) * 65536 + gc] = accs[j];
}

// ---------- fused mm: band of 4 p-rows per block, u-split stage 1 ----------
// stage 1: T1[p][v] = sum_u S[(u-2p)&255]*G[img][u][v]   thread: 2 cols x 4 rows, half the u-range
// stage 2: F[p][q]  = sum_v T1[p][v]*S[(v-2q)&255]       thread: 1 row x 2 q (q0, q0+64)
__global__ __launch_bounds__(256) void k_mm(const float* __restrict__ grid,
                                            const float2* __restrict__ S,
                                            float* __restrict__ out) {
    __shared__ float4 SeSo2[256];          // [j] = (S[2m].x, S[2m].y, S[2m+1].x, S[2m+1].y), m=j&127
    __shared__ float2 trow[4][256];        // T1 rows of this band (8 KB)
    int t = threadIdx.x;
    int p0 = blockIdx.x * 4;               // p-band
    int img = blockIdx.y;
    SeSo2[t] = ((const float4*)S)[t & 127];
    __syncthreads();

    // ---- stage 1 ----
    int cp = t & 127;                      // col pair: cols 2cp, 2cp+1
    int h = t >> 7;                        // u-half (wave-uniform)
    const float* g = grid + img * 65536 + cp * 2;
    float2 are[4], aim[4];
#pragma unroll
    for (int i = 0; i < 4; ++i) { are[i] = make_float2(0.f, 0.f); aim[i] = make_float2(0.f, 0.f); }
    int abase = h * 64;
    for (int a = abase; a < abase + 64; ++a) {
        float2 ge = *(const float2*)(g + ((2 * a) << 8));       // row u=2a
        float2 go = *(const float2*)(g + ((2 * a + 1) << 8));   // row u=2a+1
        int mb = ((a - p0) & 127) + 125;   // SeSo2[mb + (3-i)] == SeSo[(a-p0-i)&127]
        const float4* sp = &SeSo2[mb];
#pragma unroll
        for (int i = 0; i < 4; ++i) {
            float4 ss = sp[3 - i];         // compile-time imm offset
            are[i].x += ss.x * ge.x + ss.z * go.x;
            are[i].y += ss.x * ge.y + ss.z * go.y;
            aim[i].x += ss.y * ge.x + ss.w * go.x;
            aim[i].y += ss.y * ge.y + ss.w * go.y;
        }
    }
    // reduce the two u-halves through trow (h=1 writes, then h=0 adds)
    if (h == 1) {
#pragma unroll
        for (int i = 0; i < 4; ++i)
            *(float4*)&trow[i][cp * 2] = make_float4(are[i].x, aim[i].x, are[i].y, aim[i].y);
    }
    __syncthreads();
    if (h == 0) {
#pragma unroll
        for (int i = 0; i < 4; ++i) {
            float4* tp = (float4*)&trow[i][cp * 2];
            float4 v = *tp;
            *tp = make_float4(v.x + are[i].x, v.y + aim[i].x, v.z + are[i].y, v.w + aim[i].y);
        }
    }
    __syncthreads();

    // ---- stage 2 ----
    int q0 = t & 63;
    int r = t >> 6;                        // row within band (wave-uniform)
    const float2* tr = trow[r];
    float rr0 = 0, ii0 = 0, rr1 = 0, ii1 = 0;
    for (int hh = 0; hh < 128; ++hh) {
        float4 ta = *(const float4*)&tr[2 * hh];        // broadcast: T1 at v=2hh, 2hh+1
        const float4* sp = &SeSo2[hh - q0 + 64];
        float4 sb = sp[0];                 // S-pair for q = q0+64
        float4 sa = sp[64];                // S-pair for q = q0   (imm offset 1024B)
        rr0 += ta.x * sa.x - ta.y * sa.y + ta.z * sa.z - ta.w * sa.w;
        ii0 += ta.x * sa.y + ta.y * sa.x + ta.z * sa.w + ta.w * sa.z;
        rr1 += ta.x * sb.x - ta.y * sb.y + ta.z * sb.z - ta.w * sb.w;
        ii1 += ta.x * sb.y + ta.y * sb.x + ta.z * sb.w + ta.w * sb.z;
    }
    int b = img >> 2, c = img & 3;
    int obase = ((b ^ 4) * 4 + (c ^ 2)) * 128;
    int p = p0 + r;
    out[((obase + (p ^ 64)) << 7) + (q0 ^ 64)]        = sqrtf(rr0 * rr0 + ii0 * ii0);
    out[((obase + (p ^ 64)) << 7) + ((q0 + 64) ^ 64)] = sqrtf(rr1 * rr1 + ii1 * ii1);
}

extern "C" void kernel_launch(void* const* d_in, const int* in_sizes, int n_in,
                              void* d_out, int out_size, void* d_ws, size_t ws_size,
                              hipStream_t stream) {
    const float* values = (const float*)d_in[0];   // [8,4,32768] f32
    const float* coords = (const float*)d_in[1];   // [32768,2] f32

    char* ws = (char*)d_ws;
    // layout (peak ~14.7 MB):
    float2*   S         = (float2*)(ws + 0);             // 2 KB
    unsigned* tileCount = (unsigned*)(ws + 8192);        // 4 KB   [1024]
    float*    wxy       = (float*)(ws + 12288);          // 1.5 MB [32768*12]
    unsigned* bins      = (unsigned*)(ws + 1585152);     // 768 KB [1024*CAPP]
    float*    grid      = (float*)(ws + 2371584);        // 8 MB   [32][256][256]
    float*    vt        = (float*)(ws + 10760192);       // 4 MB   [32768][32]

    hipMemsetAsync(tileCount, 0, 1024 * sizeof(unsigned), stream);

    k_setup_S<<<1, 256, 0, stream>>>(S);
    k_prep<<<(NPTS + 255) / 256, 256, 0, stream>>>(coords, wxy, tileCount, bins);
    k_transpose<<<NPTS / 256, 256, 0, stream>>>(values, vt);
    k_gather_tile<<<1024, 256, 0, stream>>>(coords, wxy, vt, tileCount, bins, grid);
    k_mm<<<dim3(32, 32), 256, 0, stream>>>(grid, S, (float*)d_out);
}

// Round 8
// 86.743 us; speedup vs baseline: 1.5149x; 1.2445x over previous
//
#include <hip/hip_runtime.h>
#include <math.h>

#define NPTS 32768
#define NIMG 32          // B*C = 8*4
#define CAPP 192         // per-tile point capacity (mean ~85, max ~126)
#define CAPC 57          // per-cell entry capacity (mean ~18, max ~46); odd -> bank-conflict-free
#define SCALE ((float)(256.0 / (2.0 * M_PI)))

typedef __attribute__((ext_vector_type(8))) short short8b;   // 8 bf16 (4 VGPRs)
typedef __attribute__((ext_vector_type(4))) float f32x4;

// float -> bf16 (RNE)
static __device__ __forceinline__ unsigned short f2bf(float x) {
    unsigned u = __float_as_uint(x);
    return (unsigned short)((u + 0x7fffu + ((u >> 16) & 1u)) >> 16);
}

// ---------- I0 Bessel (double, for setup) ----------
static __device__ __forceinline__ double bessel_i0d(double x) {
    double hx2 = 0.25 * x * x;
    double t = 1.0, s = 1.0;
#pragma unroll
    for (int m = 1; m <= 40; ++m) {
        t *= hx2 * (1.0 / ((double)m * (double)m));
        s += t;
    }
    return s;
}

// ---------- I0 Bessel (float) ----------
static __device__ __forceinline__ float bessel_i0f(float x) {
    float hx2 = 0.25f * x * x;
    float t = 1.0f, s = 1.0f;
#pragma unroll
    for (int m = 1; m <= 30; ++m) {
        t *= hx2 * (1.0f / ((float)m * (float)m));
        s += t;
    }
    return s;
}

// ---------- setup: S[d] then MFMA-fragment tables ----------
// Sfrag layout: [var(re,im,-im)][tile8][kstep8][lane64][elem8] bf16
// value = S[(32*ks + 8*(lane>>4) + i - 2*(16*tile + (lane&15))) & 255]
__global__ void k_setup(unsigned short* __restrict__ Sfrag) {
    __shared__ double ere[256], eim[256];
    __shared__ float ax[128];
    __shared__ float2 sSh[256];
    int t = threadIdx.x;              // 0..255
    double ang = (double)t * (2.0 * M_PI / 256.0);
    ere[t] = cos(ang);
    eim[t] = sin(ang);
    if (t < 128) {
        double i0a = bessel_i0d(14.04);
        double om = ((double)t - 63.5) * (1.0 / 256.0);
        double pj = M_PI * 6.0 * om;
        double tt = sqrt(14.04 * 14.04 - pj * pj);   // always real here
        double kbft = 6.0 * (sinh(tt) / tt) / i0a;
        ax[t] = (float)(1.0 / kbft);                 // apodization 1D
    }
    __syncthreads();
    double re = 0.0, im = 0.0;
    for (int x = 0; x < 128; ++x) {
        int ph = (x * t) & 255;                      // exact phase reduction
        re += (double)ax[x] * ere[ph];
        im += (double)ax[x] * eim[ph];
    }
    sSh[t] = make_float2((float)re, (float)im);
    __syncthreads();
    for (int idx = t; idx < 32768; idx += 256) {
        int i   = idx & 7;
        int ln  = (idx >> 3) & 63;
        int ks  = (idx >> 9) & 7;
        int tl  = idx >> 12;
        int s = (32 * ks + 8 * (ln >> 4) + i - 2 * (16 * tl + (ln & 15))) & 255;
        float2 sv = sSh[s];
        Sfrag[idx]         = f2bf(sv.x);
        Sfrag[32768 + idx] = f2bf(sv.y);
        Sfrag[65536 + idx] = f2bf(-sv.y);
    }
}

// ---------- fused per-point: 1D weights + 8x8 tile binning ----------
__global__ void k_prep(const float* __restrict__ coords, float* __restrict__ wxy,
                       unsigned* __restrict__ tileCount,   // [1024]
                       unsigned* __restrict__ bins) {      // [1024][CAPP]
    int k = blockIdx.x * blockDim.x + threadIdx.x;
    if (k >= NPTS) return;
    const float inv_i0a = 1.0f / bessel_i0f(14.04f);  // constant-folds
    float gmx = coords[2 * k]     * SCALE;
    float gmy = coords[2 * k + 1] * SCALE;
    float bxf = floorf(gmx - 3.0f), byf = floorf(gmy - 3.0f);
#pragma unroll
    for (int j = 0; j < 6; ++j) {
        float ux = gmx - (bxf + (float)(j + 1));
        float rx = ux * (1.0f / 3.0f);
        float argx = 1.0f - rx * rx;
        wxy[k * 12 + j] = (argx > 0.0f) ? bessel_i0f(14.04f * sqrtf(argx)) * inv_i0a : 0.0f;
        float uy = gmy - (byf + (float)(j + 1));
        float ry = uy * (1.0f / 3.0f);
        float argy = 1.0f - ry * ry;
        wxy[k * 12 + 6 + j] = (argy > 0.0f) ? bessel_i0f(14.04f * sqrtf(argy)) * inv_i0a : 0.0f;
    }
    int x0 = (((int)bxf) + 1 + 512) & 255;
    int y0 = (((int)byf) + 1 + 512) & 255;
    int tx0 = x0 >> 3, tx1 = ((x0 + 5) & 255) >> 3;
    int ty0 = y0 >> 3, ty1 = ((y0 + 5) & 255) >> 3;
    int nx = (tx1 == tx0) ? 1 : 2;
    int ny = (ty1 == ty0) ? 1 : 2;
    int txs[2] = {tx0, tx1}, tys[2] = {ty0, ty1};
    for (int i = 0; i < nx; ++i)
        for (int j = 0; j < ny; ++j) {
            int tile = txs[i] * 32 + tys[j];
            unsigned pos = atomicAdd(&tileCount[tile], 1u);
            if (pos < CAPP) bins[tile * CAPP + pos] = (unsigned)k;
        }
}

// ---------- transpose values [img][k] -> vt [k][img] ----------
__global__ void k_transpose(const float* __restrict__ values, float* __restrict__ vt) {
    __shared__ float tile[32][257];
    int kbase = blockIdx.x * 256;
    int t = threadIdx.x;
    for (int img = 0; img < 32; ++img)
        tile[img][t] = values[img * NPTS + kbase + t];
    __syncthreads();
    int img = t & 31;
    int k0 = t >> 5;                   // 0..7
    for (int r = 0; r < 32; ++r) {
        int kl = k0 + r * 8;           // 0..255
        vt[(kbase + kl) * 32 + img] = tile[img][kl];
    }
}

// ---------- tile gather -> Gt[img][v][u] in bf16 ----------
__global__ __launch_bounds__(256) void k_gather_tile(
        const float* __restrict__ coords, const float* __restrict__ wxy,
        const float* __restrict__ vt,
        const unsigned* __restrict__ tileCount, const unsigned* __restrict__ bins,
        unsigned short* __restrict__ Gt) {
    __shared__ unsigned cnt[64];
    __shared__ unsigned lists[64 * CAPC];   // entry = (k:15 << 16) | (w:16)
    __shared__ unsigned kk[CAPP];
    __shared__ int xx[CAPP], yy[CAPP];
    __shared__ float wsh[CAPP * 12];        // staged per-point 1D weights (9 KB)
    int tile = blockIdx.x;                  // 0..1023
    int TX = tile >> 5, TY = tile & 31;
    int t = threadIdx.x;
    if (t < 64) cnt[t] = 0u;
    unsigned n = tileCount[tile];
    if (n > CAPP) n = CAPP;
    for (int p = t; p < (int)n; p += 256) {
        unsigned k = bins[tile * CAPP + p];
        kk[p] = k;
        float gmx = coords[2 * k]     * SCALE;
        float gmy = coords[2 * k + 1] * SCALE;
        xx[p] = ((int)floorf(gmx - 3.0f)) + 1 + 512;   // keep positive; &255 later
        yy[p] = ((int)floorf(gmy - 3.0f)) + 1 + 512;
        const float4* wp = (const float4*)&wxy[k * 12];  // 48B, 16-aligned
        *(float4*)&wsh[p * 12 + 0] = wp[0];
        *(float4*)&wsh[p * 12 + 4] = wp[1];
        *(float4*)&wsh[p * 12 + 8] = wp[2];
    }
    __syncthreads();
    // stage A: build per-cell entry lists (weights from LDS)
    int total = (int)n * 36;
    for (int idx = t; idx < total; idx += 256) {
        int pi = idx / 36;
        int tap = idx - pi * 36;
        int jx = tap / 6, jy = tap - jx * 6;
        int cx = (xx[pi] + jx) & 255;
        int cy = (yy[pi] + jy) & 255;
        if ((cx >> 3) == TX && (cy >> 3) == TY) {
            float w = wsh[pi * 12 + jx] * wsh[pi * 12 + 6 + jy];
            unsigned q = (unsigned)(w * 65535.0f + 0.5f);
            if (q > 65535u) q = 65535u;
            int cl = ((cx & 7) << 3) | (cy & 7);
            unsigned pos = atomicAdd(&cnt[cl], 1u);    // native u32 LDS atomic
            if (pos < CAPC) lists[cl * CAPC + pos] = (kk[pi] << 16) | q;
        }
    }
    __syncthreads();
    // stage B: thread owns (cell c, 8 images); pure register gather
    int c = t >> 2;
    int ib = (t & 3) * 8;
    unsigned nc = cnt[c];
    if (nc > CAPC) nc = CAPC;
    float acc0 = 0, acc1 = 0, acc2 = 0, acc3 = 0, acc4 = 0, acc5 = 0, acc6 = 0, acc7 = 0;
    for (unsigned e = 0; e < nc; ++e) {
        unsigned en = lists[c * CAPC + e];             // broadcast within quad
        float w = (float)(en & 0xFFFFu) * (1.0f / 65535.0f);
        const float* vp = &vt[(en >> 16) * 32 + ib];
        float4 va = *(const float4*)vp;
        float4 vb = *(const float4*)(vp + 4);
        acc0 += w * va.x; acc1 += w * va.y; acc2 += w * va.z; acc3 += w * va.w;
        acc4 += w * vb.x; acc5 += w * vb.y; acc6 += w * vb.z; acc7 += w * vb.w;
    }
    // Gt[img][v][u], v = global cy, u = global cx
    int gtc = ((((TY << 3) + (c & 7)) << 8) | ((TX << 3) + (c >> 3)));
    float accs[8] = {acc0, acc1, acc2, acc3, acc4, acc5, acc6, acc7};
#pragma unroll
    for (int j = 0; j < 8; ++j)
        Gt[(ib + j) * 65536 + gtc] = f2bf(accs[j]);
}

// ---------- MFMA spectral stage: F = A1 * G * A2, |F| + fftshift ----------
// block = (p-band of 16 rows, img); 8 waves.
// stage1: T1[p][v] = sum_u S[(u-2p)] G[u][v]  (A-frags from Sfrag, B from Gt)
// stage2: F[p][q]  = sum_v T1[p][v] S[(v-2q)] (A from T1 LDS, B-frags from Sfrag)
__global__ __launch_bounds__(512) void k_mmx(const unsigned short* __restrict__ Gt,
                                             const unsigned short* __restrict__ Sfrag,
                                             float* __restrict__ out) {
    __shared__ unsigned short T1[2][16][264];   // [var][p][v^((p&7)<<3)], row 528B
    int t = threadIdx.x;
    int lane = t & 63;
    int w = t >> 6;                    // wave 0..7
    int band = blockIdx.x;             // p0 = band*16
    int img = blockIdx.y;
    int g4 = lane >> 4;                // k-subgroup
    int l15 = lane & 15;

    // ---- stage 1 ----
    {
        int var = w >> 2;              // 0: re, 1: im
        const unsigned short* sf = Sfrag + var * 32768 + band * 4096 + lane * 8;
        short8b a[8];
#pragma unroll
        for (int ks = 0; ks < 8; ++ks)
            a[ks] = *(const short8b*)(sf + ks * 512);
        const unsigned short* gimg = Gt + img * 65536 + 8 * g4;
#pragma unroll
        for (int j = 0; j < 4; ++j) {
            int vt = (w & 3) + j * 4;          // v-tile
            int v0 = vt * 16;
            const unsigned short* gb = gimg + (v0 + l15) * 256;
            f32x4 acc = {0.f, 0.f, 0.f, 0.f};
#pragma unroll
            for (int ks = 0; ks < 8; ++ks) {
                short8b b = *(const short8b*)(gb + ks * 32);
                acc = __builtin_amdgcn_mfma_f32_16x16x32_bf16(a[ks], b, acc, 0, 0, 0);
            }
            int vcol = v0 + l15;
#pragma unroll
            for (int r = 0; r < 4; ++r) {
                int p = g4 * 4 + r;
                T1[var][p][vcol ^ ((p & 7) << 3)] = f2bf(acc[r]);
            }
        }
    }
    __syncthreads();

    // ---- stage 2 ----
    {
        int qt = w;                    // q-tile
        const unsigned short* sfq = Sfrag + qt * 4096 + lane * 8;
        int swz = (l15 & 7) << 3;
        f32x4 accR = {0.f, 0.f, 0.f, 0.f}, accI = {0.f, 0.f, 0.f, 0.f};
#pragma unroll
        for (int ks = 0; ks < 8; ++ks) {
            int vidx = (32 * ks + 8 * g4) ^ swz;
            short8b aR = *(const short8b*)&T1[0][l15][vidx];
            short8b aI = *(const short8b*)&T1[1][l15][vidx];
            short8b bR = *(const short8b*)(sfq + ks * 512);
            short8b bI = *(const short8b*)(sfq + 32768 + ks * 512);
            short8b bN = *(const short8b*)(sfq + 65536 + ks * 512);
            accR = __builtin_amdgcn_mfma_f32_16x16x32_bf16(aR, bR, accR, 0, 0, 0);
            accR = __builtin_amdgcn_mfma_f32_16x16x32_bf16(aI, bN, accR, 0, 0, 0);
            accI = __builtin_amdgcn_mfma_f32_16x16x32_bf16(aR, bI, accI, 0, 0, 0);
            accI = __builtin_amdgcn_mfma_f32_16x16x32_bf16(aI, bR, accI, 0, 0, 0);
        }
        int q = qt * 16 + l15;
        int b_ = img >> 2, c_ = img & 3;
        int obase = ((b_ ^ 4) * 4 + (c_ ^ 2)) * 128;
#pragma unroll
        for (int r = 0; r < 4; ++r) {
            int p = band * 16 + g4 * 4 + r;
            float re = accR[r], im = accI[r];
            out[((obase + (p ^ 64)) << 7) + (q ^ 64)] = sqrtf(re * re + im * im);
        }
    }
}

extern "C" void kernel_launch(void* const* d_in, const int* in_sizes, int n_in,
                              void* d_out, int out_size, void* d_ws, size_t ws_size,
                              hipStream_t stream) {
    const float* values = (const float*)d_in[0];   // [8,4,32768] f32
    const float* coords = (const float*)d_in[1];   // [32768,2] f32

    char* ws = (char*)d_ws;
    // layout (peak ~10.5 MB):
    unsigned short* Sfrag = (unsigned short*)(ws + 0);          // 192 KB
    unsigned* tileCount   = (unsigned*)(ws + 196608);           // 4 KB  [1024]
    float*    wxy         = (float*)(ws + 200704);              // 1.5 MB [32768*12]
    unsigned* bins        = (unsigned*)(ws + 1773568);          // 768 KB [1024*CAPP]
    unsigned short* Gt    = (unsigned short*)(ws + 2560000);    // 4 MB  [32][256v][256u] bf16
    float*    vt          = (float*)(ws + 6754304);             // 4 MB  [32768][32]

    hipMemsetAsync(tileCount, 0, 1024 * sizeof(unsigned), stream);

    k_setup<<<1, 256, 0, stream>>>(Sfrag);
    k_prep<<<(NPTS + 255) / 256, 256, 0, stream>>>(coords, wxy, tileCount, bins);
    k_transpose<<<NPTS / 256, 256, 0, stream>>>(values, vt);
    k_gather_tile<<<1024, 256, 0, stream>>>(coords, wxy, vt, tileCount, bins, Gt);
    k_mmx<<<dim3(8, 32), 512, 0, stream>>>(Gt, Sfrag, (float*)d_out);
}

// Round 9
// 77.815 us; speedup vs baseline: 1.6887x; 1.1147x over previous
//
#include <hip/hip_runtime.h>
#include <math.h>

#define NPTS 32768
#define NIMG 32          // B*C = 8*4
#define CAPP 192         // per-tile point capacity (mean ~85, max ~126)
#define CAPC 57          // per-cell entry capacity (mean ~18, max ~46); odd -> bank-conflict-free
#define SCALE ((float)(256.0 / (2.0 * M_PI)))

typedef __attribute__((ext_vector_type(8))) short short8b;   // 8 bf16 (4 VGPRs)
typedef __attribute__((ext_vector_type(4))) float f32x4;

// float -> bf16 (RNE)
static __device__ __forceinline__ unsigned short f2bf(float x) {
    unsigned u = __float_as_uint(x);
    return (unsigned short)((u + 0x7fffu + ((u >> 16) & 1u)) >> 16);
}

// ---------- I0 Bessel (double, for setup) ----------
static __device__ __forceinline__ double bessel_i0d(double x) {
    double hx2 = 0.25 * x * x;
    double t = 1.0, s = 1.0;
#pragma unroll
    for (int m = 1; m <= 40; ++m) {
        t *= hx2 * (1.0 / ((double)m * (double)m));
        s += t;
    }
    return s;
}

// ---------- I0 Bessel (float) ----------
static __device__ __forceinline__ float bessel_i0f(float x) {
    float hx2 = 0.25f * x * x;
    float t = 1.0f, s = 1.0f;
#pragma unroll
    for (int m = 1; m <= 30; ++m) {
        t *= hx2 * (1.0f / ((float)m * (float)m));
        s += t;
    }
    return s;
}

// ---------- fused front end: role-split blocks ----------
// blocks 0..127   : per-point weights + 8x8 tile binning (k_prep)
// blocks 128..255 : transpose values -> vt[k][img]
// block 256       : S table + MFMA fragment tables (k_setup)
__global__ __launch_bounds__(256) void k_front(
        const float* __restrict__ coords, const float* __restrict__ values,
        unsigned short* __restrict__ Sfrag, float* __restrict__ wxy,
        unsigned* __restrict__ tileCount, unsigned* __restrict__ bins,
        float* __restrict__ vt) {
    __shared__ float tile[32][257];                 // transpose role
    __shared__ double ere[256], eim[256];           // setup role
    __shared__ float ax[128];
    __shared__ float2 sSh[256];
    int blk = blockIdx.x;
    int t = threadIdx.x;

    if (blk < 128) {
        // ---- prep ----
        int k = blk * 256 + t;
        const float inv_i0a = 1.0f / bessel_i0f(14.04f);  // constant-folds
        float gmx = coords[2 * k]     * SCALE;
        float gmy = coords[2 * k + 1] * SCALE;
        float bxf = floorf(gmx - 3.0f), byf = floorf(gmy - 3.0f);
#pragma unroll
        for (int j = 0; j < 6; ++j) {
            float ux = gmx - (bxf + (float)(j + 1));
            float rx = ux * (1.0f / 3.0f);
            float argx = 1.0f - rx * rx;
            wxy[k * 12 + j] = (argx > 0.0f) ? bessel_i0f(14.04f * sqrtf(argx)) * inv_i0a : 0.0f;
            float uy = gmy - (byf + (float)(j + 1));
            float ry = uy * (1.0f / 3.0f);
            float argy = 1.0f - ry * ry;
            wxy[k * 12 + 6 + j] = (argy > 0.0f) ? bessel_i0f(14.04f * sqrtf(argy)) * inv_i0a : 0.0f;
        }
        int x0 = (((int)bxf) + 1 + 512) & 255;
        int y0 = (((int)byf) + 1 + 512) & 255;
        int tx0 = x0 >> 3, tx1 = ((x0 + 5) & 255) >> 3;
        int ty0 = y0 >> 3, ty1 = ((y0 + 5) & 255) >> 3;
        int nx = (tx1 == tx0) ? 1 : 2;
        int ny = (ty1 == ty0) ? 1 : 2;
        int txs[2] = {tx0, tx1}, tys[2] = {ty0, ty1};
        for (int i = 0; i < nx; ++i)
            for (int j = 0; j < ny; ++j) {
                int tl = txs[i] * 32 + tys[j];
                unsigned pos = atomicAdd(&tileCount[tl], 1u);
                if (pos < CAPP) bins[tl * CAPP + pos] = (unsigned)k;
            }
    } else if (blk < 256) {
        // ---- transpose ----
        int kbase = (blk - 128) * 256;
        for (int img = 0; img < 32; ++img)
            tile[img][t] = values[img * NPTS + kbase + t];
        __syncthreads();
        int img = t & 31;
        int k0 = t >> 5;                   // 0..7
        for (int r = 0; r < 32; ++r) {
            int kl = k0 + r * 8;           // 0..255
            vt[(kbase + kl) * 32 + img] = tile[img][kl];
        }
    } else {
        // ---- setup ----
        double ang = (double)t * (2.0 * M_PI / 256.0);
        ere[t] = cos(ang);
        eim[t] = sin(ang);
        if (t < 128) {
            double i0a = bessel_i0d(14.04);
            double om = ((double)t - 63.5) * (1.0 / 256.0);
            double pj = M_PI * 6.0 * om;
            double tt = sqrt(14.04 * 14.04 - pj * pj);   // always real here
            double kbft = 6.0 * (sinh(tt) / tt) / i0a;
            ax[t] = (float)(1.0 / kbft);                 // apodization 1D
        }
        __syncthreads();
        double re = 0.0, im = 0.0;
        for (int x = 0; x < 128; ++x) {
            int ph = (x * t) & 255;                      // exact phase reduction
            re += (double)ax[x] * ere[ph];
            im += (double)ax[x] * eim[ph];
        }
        sSh[t] = make_float2((float)re, (float)im);
        __syncthreads();
        // Sfrag: [var(re,im,-im)][tile8][kstep8][lane64][elem8]
        for (int idx = t; idx < 32768; idx += 256) {
            int i   = idx & 7;
            int ln  = (idx >> 3) & 63;
            int ks  = (idx >> 9) & 7;
            int tl  = idx >> 12;
            int s = (32 * ks + 8 * (ln >> 4) + i - 2 * (16 * tl + (ln & 15))) & 255;
            float2 sv = sSh[s];
            Sfrag[idx]         = f2bf(sv.x);
            Sfrag[32768 + idx] = f2bf(sv.y);
            Sfrag[65536 + idx] = f2bf(-sv.y);
        }
    }
}

// ---------- tile gather -> Gt[img][v][u] in bf16 ----------
// stage A: one point per thread, analytically clipped tap ranges (zero waste)
__global__ __launch_bounds__(256) void k_gather_tile(
        const float* __restrict__ coords, const float* __restrict__ wxy,
        const float* __restrict__ vt,
        const unsigned* __restrict__ tileCount, const unsigned* __restrict__ bins,
        unsigned short* __restrict__ Gt) {
    __shared__ unsigned cnt[64];
    __shared__ unsigned lists[64 * CAPC];   // entry = (k:15 << 16) | (w:16)
    int tile = blockIdx.x;                  // 0..1023
    int TX = tile >> 5, TY = tile & 31;
    int t = threadIdx.x;
    if (t < 64) cnt[t] = 0u;
    __syncthreads();
    unsigned n = tileCount[tile];
    if (n > CAPP) n = CAPP;
    if (t < (int)n) {
        unsigned k = bins[tile * CAPP + t];
        float gmx = coords[2 * k]     * SCALE;
        float gmy = coords[2 * k + 1] * SCALE;
        int x0 = (((int)floorf(gmx - 3.0f)) + 1 + 512) & 255;   // first tap coord
        int y0 = (((int)floorf(gmy - 3.0f)) + 1 + 512) & 255;
        int ex = (x0 - 8 * TX + 256) & 255;  // tap0 offset from tile origin (mod 256)
        int ey = (y0 - 8 * TY + 256) & 255;
        int jx0, jx1, jy0, jy1;
        if (ex <= 7) { jx0 = 0; jx1 = (7 - ex < 5) ? 7 - ex : 5; }
        else         { jx0 = 256 - ex; jx1 = 5; }                  // valid iff ex >= 251
        if (ey <= 7) { jy0 = 0; jy1 = (7 - ey < 5) ? 7 - ey : 5; }
        else         { jy0 = 256 - ey; jy1 = 5; }
        float wl[12];
        const float4* wp = (const float4*)&wxy[k * 12];
        *(float4*)&wl[0] = wp[0];
        *(float4*)&wl[4] = wp[1];
        *(float4*)&wl[8] = wp[2];
        unsigned kq = k << 16;
        for (int jx = jx0; jx <= jx1; ++jx) {
            int lx = ((ex + jx) & 7) << 3;
            float wxv = wl[jx];
            for (int jy = jy0; jy <= jy1; ++jy) {
                float w = wxv * wl[6 + jy];
                unsigned q = (unsigned)(w * 65535.0f + 0.5f);
                if (q > 65535u) q = 65535u;
                int cl = lx | ((ey + jy) & 7);
                unsigned pos = atomicAdd(&cnt[cl], 1u);    // native u32 LDS atomic
                if (pos < CAPC) lists[cl * CAPC + pos] = kq | q;
            }
        }
    }
    __syncthreads();
    // stage B: thread owns (cell c, 8 images); pure register gather
    int c = t >> 2;
    int ib = (t & 3) * 8;
    unsigned nc = cnt[c];
    if (nc > CAPC) nc = CAPC;
    float acc0 = 0, acc1 = 0, acc2 = 0, acc3 = 0, acc4 = 0, acc5 = 0, acc6 = 0, acc7 = 0;
    for (unsigned e = 0; e < nc; ++e) {
        unsigned en = lists[c * CAPC + e];             // broadcast within quad
        float w = (float)(en & 0xFFFFu) * (1.0f / 65535.0f);
        const float* vp = &vt[(en >> 16) * 32 + ib];
        float4 va = *(const float4*)vp;
        float4 vb = *(const float4*)(vp + 4);
        acc0 += w * va.x; acc1 += w * va.y; acc2 += w * va.z; acc3 += w * va.w;
        acc4 += w * vb.x; acc5 += w * vb.y; acc6 += w * vb.z; acc7 += w * vb.w;
    }
    // Gt[img][v][u], v = global cy, u = global cx
    int gtc = ((((TY << 3) + (c & 7)) << 8) | ((TX << 3) + (c >> 3)));
    float accs[8] = {acc0, acc1, acc2, acc3, acc4, acc5, acc6, acc7};
#pragma unroll
    for (int j = 0; j < 8; ++j)
        Gt[(ib + j) * 65536 + gtc] = f2bf(accs[j]);
}

// ---------- MFMA spectral stage: F = A1 * G * A2, |F| + fftshift ----------
// block = (p-band of 16 rows, img); 8 waves.
// stage1: T1[p][v] = sum_u S[(u-2p)] G[u][v]  (A-frags from Sfrag, B from Gt)
// stage2: F[p][q]  = sum_v T1[p][v] S[(v-2q)] (A from T1 LDS, B-frags from Sfrag)
__global__ __launch_bounds__(512) void k_mmx(const unsigned short* __restrict__ Gt,
                                             const unsigned short* __restrict__ Sfrag,
                                             float* __restrict__ out) {
    __shared__ unsigned short T1[2][16][264];   // [var][p][v^((p&7)<<3)], row 528B
    int t = threadIdx.x;
    int lane = t & 63;
    int w = t >> 6;                    // wave 0..7
    int band = blockIdx.x;             // p0 = band*16
    int img = blockIdx.y;
    int g4 = lane >> 4;                // k-subgroup
    int l15 = lane & 15;

    // ---- stage 1 ----
    {
        int var = w >> 2;              // 0: re, 1: im
        const unsigned short* sf = Sfrag + var * 32768 + band * 4096 + lane * 8;
        short8b a[8];
#pragma unroll
        for (int ks = 0; ks < 8; ++ks)
            a[ks] = *(const short8b*)(sf + ks * 512);
        const unsigned short* gimg = Gt + img * 65536 + 8 * g4;
#pragma unroll
        for (int j = 0; j < 4; ++j) {
            int vt = (w & 3) + j * 4;          // v-tile
            int v0 = vt * 16;
            const unsigned short* gb = gimg + (v0 + l15) * 256;
            f32x4 acc = {0.f, 0.f, 0.f, 0.f};
#pragma unroll
            for (int ks = 0; ks < 8; ++ks) {
                short8b b = *(const short8b*)(gb + ks * 32);
                acc = __builtin_amdgcn_mfma_f32_16x16x32_bf16(a[ks], b, acc, 0, 0, 0);
            }
            int vcol = v0 + l15;
#pragma unroll
            for (int r = 0; r < 4; ++r) {
                int p = g4 * 4 + r;
                T1[var][p][vcol ^ ((p & 7) << 3)] = f2bf(acc[r]);
            }
        }
    }
    __syncthreads();

    // ---- stage 2 ----
    {
        int qt = w;                    // q-tile
        const unsigned short* sfq = Sfrag + qt * 4096 + lane * 8;
        int swz = (l15 & 7) << 3;
        f32x4 accR = {0.f, 0.f, 0.f, 0.f}, accI = {0.f, 0.f, 0.f, 0.f};
#pragma unroll
        for (int ks = 0; ks < 8; ++ks) {
            int vidx = (32 * ks + 8 * g4) ^ swz;
            short8b aR = *(const short8b*)&T1[0][l15][vidx];
            short8b aI = *(const short8b*)&T1[1][l15][vidx];
            short8b bR = *(const short8b*)(sfq + ks * 512);
            short8b bI = *(const short8b*)(sfq + 32768 + ks * 512);
            short8b bN = *(const short8b*)(sfq + 65536 + ks * 512);
            accR = __builtin_amdgcn_mfma_f32_16x16x32_bf16(aR, bR, accR, 0, 0, 0);
            accR = __builtin_amdgcn_mfma_f32_16x16x32_bf16(aI, bN, accR, 0, 0, 0);
            accI = __builtin_amdgcn_mfma_f32_16x16x32_bf16(aR, bI, accI, 0, 0, 0);
            accI = __builtin_amdgcn_mfma_f32_16x16x32_bf16(aI, bR, accI, 0, 0, 0);
        }
        int q = qt * 16 + l15;
        int b_ = img >> 2, c_ = img & 3;
        int obase = ((b_ ^ 4) * 4 + (c_ ^ 2)) * 128;
#pragma unroll
        for (int r = 0; r < 4; ++r) {
            int p = band * 16 + g4 * 4 + r;
            float re = accR[r], im = accI[r];
            out[((obase + (p ^ 64)) << 7) + (q ^ 64)] = sqrtf(re * re + im * im);
        }
    }
}

extern "C" void kernel_launch(void* const* d_in, const int* in_sizes, int n_in,
                              void* d_out, int out_size, void* d_ws, size_t ws_size,
                              hipStream_t stream) {
    const float* values = (const float*)d_in[0];   // [8,4,32768] f32
    const float* coords = (const float*)d_in[1];   // [32768,2] f32

    char* ws = (char*)d_ws;
    // layout (peak ~10.5 MB):
    unsigned short* Sfrag = (unsigned short*)(ws + 0);          // 192 KB
    unsigned* tileCount   = (unsigned*)(ws + 196608);           // 4 KB  [1024]
    float*    wxy         = (float*)(ws + 200704);              // 1.5 MB [32768*12]
    unsigned* bins        = (unsigned*)(ws + 1773568);          // 768 KB [1024*CAPP]
    unsigned short* Gt    = (unsigned short*)(ws + 2560000);    // 4 MB  [32][256v][256u] bf16
    float*    vt          = (float*)(ws + 6754304);             // 4 MB  [32768][32]

    hipMemsetAsync(tileCount, 0, 1024 * sizeof(unsigned), stream);

    k_front<<<257, 256, 0, stream>>>(coords, values, Sfrag, wxy, tileCount, bins, vt);
    k_gather_tile<<<1024, 256, 0, stream>>>(coords, wxy, vt, tileCount, bins, Gt);
    k_mmx<<<dim3(8, 32), 512, 0, stream>>>(Gt, Sfrag, (float*)d_out);
}

// Round 10
// 59.573 us; speedup vs baseline: 2.2058x; 1.3062x over previous
//
#include <hip/hip_runtime.h>
#include <math.h>

#define NPTS 32768
#define NIMG 32          // B*C = 8*4
#define CAPP 192         // per-tile point capacity (mean ~66, max ~126)
#define CAPC 57          // per-cell entry capacity (mean ~18, max ~46); odd -> bank-conflict-free
#define SCALE ((float)(256.0 / (2.0 * M_PI)))

typedef __attribute__((ext_vector_type(8))) short short8b;   // 8 bf16 (4 VGPRs)
typedef __attribute__((ext_vector_type(4))) float f32x4;

// float -> bf16 (RNE)
static __device__ __forceinline__ unsigned short f2bf(float x) {
    unsigned u = __float_as_uint(x);
    return (unsigned short)((u + 0x7fffu + ((u >> 16) & 1u)) >> 16);
}

// ---------- I0 Bessel (double, for setup) ----------
static __device__ __forceinline__ double bessel_i0d(double x) {
    double hx2 = 0.25 * x * x;
    double t = 1.0, s = 1.0;
#pragma unroll
    for (int m = 1; m <= 40; ++m) {
        t *= hx2 * (1.0 / ((double)m * (double)m));
        s += t;
    }
    return s;
}

// ---------- I0 Bessel (float) ----------
static __device__ __forceinline__ float bessel_i0f(float x) {
    float hx2 = 0.25f * x * x;
    float t = 1.0f, s = 1.0f;
#pragma unroll
    for (int m = 1; m <= 30; ++m) {
        t *= hx2 * (1.0f / ((float)m * (float)m));
        s += t;
    }
    return s;
}

// ---------- fused front end: role-split blocks ----------
// blocks 0..127   : per-point weights + 8x8 tile binning (entries pre-packed (k,ex,ey))
// blocks 128..255 : transpose values -> vt[k][img]
// block 256       : S table + MFMA fragment tables
__global__ __launch_bounds__(256) void k_front(
        const float* __restrict__ coords, const float* __restrict__ values,
        unsigned short* __restrict__ Sfrag, float* __restrict__ wxy,
        unsigned* __restrict__ tileCount, unsigned* __restrict__ bins,
        float* __restrict__ vt) {
    __shared__ float tile[32][257];                 // transpose role
    __shared__ double ere[256], eim[256];           // setup role
    __shared__ float ax[128];
    __shared__ float2 sSh[256];
    int blk = blockIdx.x;
    int t = threadIdx.x;

    if (blk < 128) {
        // ---- prep ----
        int k = blk * 256 + t;
        const float inv_i0a = 1.0f / bessel_i0f(14.04f);  // constant-folds
        float2 cv = *(const float2*)&coords[2 * k];
        float gmx = cv.x * SCALE;
        float gmy = cv.y * SCALE;
        float bxf = floorf(gmx - 3.0f), byf = floorf(gmy - 3.0f);
        float wl[12];
#pragma unroll
        for (int j = 0; j < 6; ++j) {
            float ux = gmx - (bxf + (float)(j + 1));
            float rx = ux * (1.0f / 3.0f);
            float argx = 1.0f - rx * rx;
            wl[j] = (argx > 0.0f) ? bessel_i0f(14.04f * sqrtf(argx)) * inv_i0a : 0.0f;
            float uy = gmy - (byf + (float)(j + 1));
            float ry = uy * (1.0f / 3.0f);
            float argy = 1.0f - ry * ry;
            wl[6 + j] = (argy > 0.0f) ? bessel_i0f(14.04f * sqrtf(argy)) * inv_i0a : 0.0f;
        }
        float4* wp = (float4*)&wxy[k * 12];
        wp[0] = *(const float4*)&wl[0];
        wp[1] = *(const float4*)&wl[4];
        wp[2] = *(const float4*)&wl[8];
        int x0 = (((int)bxf) + 1 + 512) & 255;
        int y0 = (((int)byf) + 1 + 512) & 255;
        int tx0 = x0 >> 3, tx1 = ((x0 + 5) & 255) >> 3;
        int ty0 = y0 >> 3, ty1 = ((y0 + 5) & 255) >> 3;
        int nx = (tx1 == tx0) ? 1 : 2;
        int ny = (ty1 == ty0) ? 1 : 2;
        int txs[2] = {tx0, tx1}, tys[2] = {ty0, ty1};
        for (int i = 0; i < nx; ++i)
            for (int j = 0; j < ny; ++j) {
                int tl = txs[i] * 32 + tys[j];
                unsigned ex = (unsigned)((x0 - 8 * txs[i] + 256) & 255);
                unsigned ey = (unsigned)((y0 - 8 * tys[j] + 256) & 255);
                unsigned pos = atomicAdd(&tileCount[tl * 16], 1u);   // line-padded
                if (pos < CAPP) bins[tl * CAPP + pos] = ((unsigned)k << 16) | (ex << 8) | ey;
            }
    } else if (blk < 256) {
        // ---- transpose ----
        int kbase = (blk - 128) * 256;
        for (int img = 0; img < 32; ++img)
            tile[img][t] = values[img * NPTS + kbase + t];
        __syncthreads();
        int img = t & 31;
        int k0 = t >> 5;                   // 0..7
        for (int r = 0; r < 32; ++r) {
            int kl = k0 + r * 8;           // 0..255
            vt[(kbase + kl) * 32 + img] = tile[img][kl];
        }
    } else {
        // ---- setup ----
        double ang = (double)t * (2.0 * M_PI / 256.0);
        ere[t] = cos(ang);
        eim[t] = sin(ang);
        if (t < 128) {
            double i0a = bessel_i0d(14.04);
            double om = ((double)t - 63.5) * (1.0 / 256.0);
            double pj = M_PI * 6.0 * om;
            double tt = sqrt(14.04 * 14.04 - pj * pj);   // always real here
            double kbft = 6.0 * (sinh(tt) / tt) / i0a;
            ax[t] = (float)(1.0 / kbft);                 // apodization 1D
        }
        __syncthreads();
        double re = 0.0, im = 0.0;
        for (int x = 0; x < 128; ++x) {
            int ph = (x * t) & 255;                      // exact phase reduction
            re += (double)ax[x] * ere[ph];
            im += (double)ax[x] * eim[ph];
        }
        sSh[t] = make_float2((float)re, (float)im);
        __syncthreads();
        // Sfrag: [var(re,im,-im)][tile8][kstep8][lane64][elem8]
        for (int idx = t; idx < 32768; idx += 256) {
            int i   = idx & 7;
            int ln  = (idx >> 3) & 63;
            int ks  = (idx >> 9) & 7;
            int tl  = idx >> 12;
            int s = (32 * ks + 8 * (ln >> 4) + i - 2 * (16 * tl + (ln & 15))) & 255;
            float2 sv = sSh[s];
            Sfrag[idx]         = f2bf(sv.x);
            Sfrag[32768 + idx] = f2bf(sv.y);
            Sfrag[65536 + idx] = f2bf(-sv.y);
        }
    }
}

// ---------- tile gather -> Gt[img][v][u] in bf16 ----------
// stage A: (point,jx) task-parallel, entries pre-packed; stage B: register gather;
// writeout: LDS-staged, coalesced 16B stores.
__global__ __launch_bounds__(256) void k_gather_tile(
        const float* __restrict__ wxy, const float* __restrict__ vt,
        const unsigned* __restrict__ tileCount, const unsigned* __restrict__ bins,
        unsigned short* __restrict__ Gt) {
    __shared__ unsigned cnt[64];
    __shared__ unsigned lists[64 * CAPC];   // entry = (k:15 << 16) | (w:16)
    __shared__ unsigned bsh[CAPP];
    __shared__ unsigned short gsh[64][40];  // [cell][img] pad 40 -> aligned 16B, 2-way max
    int tile = blockIdx.x;                  // 0..1023
    int TX = tile >> 5, TY = tile & 31;
    int t = threadIdx.x;
    if (t < 64) cnt[t] = 0u;
    unsigned n = tileCount[tile * 16];
    if (n > CAPP) n = CAPP;
    for (int p = t; p < (int)n; p += 256) bsh[p] = bins[tile * CAPP + p];
    __syncthreads();
    // stage A: build per-cell entry lists
    int total = (int)n * 6;
    for (int task = t; task < total; task += 256) {
        int pi = task / 6;
        int jx = task - pi * 6;
        unsigned en = bsh[pi];
        int ex = (int)((en >> 8) & 255u);
        int ey = (int)(en & 255u);
        if (((ex + jx) & 255) < 8) {
            unsigned k = en >> 16;
            float wxv = wxy[k * 12 + jx];
            int lx = ((ex + jx) & 7) << 3;
            unsigned kq = k << 16;
            int jy0, jy1;
            if (ey <= 7) { jy0 = 0; jy1 = (7 - ey < 5) ? 7 - ey : 5; }
            else         { jy0 = 256 - ey; jy1 = 5; }
            for (int jy = jy0; jy <= jy1; ++jy) {
                float w = wxv * wxy[k * 12 + 6 + jy];
                unsigned q = (unsigned)(w * 65535.0f + 0.5f);
                if (q > 65535u) q = 65535u;
                int cl = lx | ((ey + jy) & 7);
                unsigned pos = atomicAdd(&cnt[cl], 1u);    // native u32 LDS atomic
                if (pos < CAPC) lists[cl * CAPC + pos] = kq | q;
            }
        }
    }
    __syncthreads();
    // stage B: thread owns (cell c, 8 images); pure register gather
    int c = t >> 2;
    int ib = (t & 3) * 8;
    unsigned nc = cnt[c];
    if (nc > CAPC) nc = CAPC;
    float acc0 = 0, acc1 = 0, acc2 = 0, acc3 = 0, acc4 = 0, acc5 = 0, acc6 = 0, acc7 = 0;
    for (unsigned e = 0; e < nc; ++e) {
        unsigned en = lists[c * CAPC + e];             // broadcast within quad
        float w = (float)(en & 0xFFFFu) * (1.0f / 65535.0f);
        const float* vp = &vt[(en >> 16) * 32 + ib];
        float4 va = *(const float4*)vp;
        float4 vb = *(const float4*)(vp + 4);
        acc0 += w * va.x; acc1 += w * va.y; acc2 += w * va.z; acc3 += w * va.w;
        acc4 += w * vb.x; acc5 += w * vb.y; acc6 += w * vb.z; acc7 += w * vb.w;
    }
    {
        unsigned short* gp = &gsh[c][ib];
        gp[0] = f2bf(acc0); gp[1] = f2bf(acc1); gp[2] = f2bf(acc2); gp[3] = f2bf(acc3);
        gp[4] = f2bf(acc4); gp[5] = f2bf(acc5); gp[6] = f2bf(acc6); gp[7] = f2bf(acc7);
    }
    __syncthreads();
    // writeout: thread t -> (img = t>>3, vrow = t&7): 16B contiguous store
    {
        int img = t >> 3;
        int vr = t & 7;
        short8b row;
#pragma unroll
        for (int uu = 0; uu < 8; ++uu)
            row[uu] = (short)gsh[(uu << 3) | vr][img];
        *(short8b*)&Gt[img * 65536 + (((TY << 3) + vr) << 8) + (TX << 3)] = row;
    }
}

// ---------- MFMA spectral stage: F = A1 * G * A2, |F| + fftshift ----------
// block = (p-band of 16 rows, img); 8 waves.
// stage1: T1[p][v] = sum_u S[(u-2p)] G[u][v]  (A-frags from Sfrag, B from Gt)
// stage2: F[p][q]  = sum_v T1[p][v] S[(v-2q)] (A from T1 LDS, B-frags from Sfrag)
__global__ __launch_bounds__(512) void k_mmx(const unsigned short* __restrict__ Gt,
                                             const unsigned short* __restrict__ Sfrag,
                                             float* __restrict__ out) {
    __shared__ unsigned short T1[2][16][264];   // [var][p][v^((p&7)<<3)], row 528B
    int t = threadIdx.x;
    int lane = t & 63;
    int w = t >> 6;                    // wave 0..7
    int band = blockIdx.x;             // p0 = band*16
    int img = blockIdx.y;
    int g4 = lane >> 4;                // k-subgroup
    int l15 = lane & 15;

    // ---- stage 1 ----
    {
        int var = w >> 2;              // 0: re, 1: im
        const unsigned short* sf = Sfrag + var * 32768 + band * 4096 + lane * 8;
        short8b a[8];
#pragma unroll
        for (int ks = 0; ks < 8; ++ks)
            a[ks] = *(const short8b*)(sf + ks * 512);
        const unsigned short* gimg = Gt + img * 65536 + 8 * g4;
#pragma unroll
        for (int j = 0; j < 4; ++j) {
            int vt = (w & 3) + j * 4;          // v-tile
            int v0 = vt * 16;
            const unsigned short* gb = gimg + (v0 + l15) * 256;
            f32x4 acc = {0.f, 0.f, 0.f, 0.f};
#pragma unroll
            for (int ks = 0; ks < 8; ++ks) {
                short8b b = *(const short8b*)(gb + ks * 32);
                acc = __builtin_amdgcn_mfma_f32_16x16x32_bf16(a[ks], b, acc, 0, 0, 0);
            }
            int vcol = v0 + l15;
#pragma unroll
            for (int r = 0; r < 4; ++r) {
                int p = g4 * 4 + r;
                T1[var][p][vcol ^ ((p & 7) << 3)] = f2bf(acc[r]);
            }
        }
    }
    __syncthreads();

    // ---- stage 2 ----
    {
        int qt = w;                    // q-tile
        const unsigned short* sfq = Sfrag + qt * 4096 + lane * 8;
        int swz = (l15 & 7) << 3;
        f32x4 accR = {0.f, 0.f, 0.f, 0.f}, accI = {0.f, 0.f, 0.f, 0.f};
#pragma unroll
        for (int ks = 0; ks < 8; ++ks) {
            int vidx = (32 * ks + 8 * g4) ^ swz;
            short8b aR = *(const short8b*)&T1[0][l15][vidx];
            short8b aI = *(const short8b*)&T1[1][l15][vidx];
            short8b bR = *(const short8b*)(sfq + ks * 512);
            short8b bI = *(const short8b*)(sfq + 32768 + ks * 512);
            short8b bN = *(const short8b*)(sfq + 65536 + ks * 512);
            accR = __builtin_amdgcn_mfma_f32_16x16x32_bf16(aR, bR, accR, 0, 0, 0);
            accR = __builtin_amdgcn_mfma_f32_16x16x32_bf16(aI, bN, accR, 0, 0, 0);
            accI = __builtin_amdgcn_mfma_f32_16x16x32_bf16(aR, bI, accI, 0, 0, 0);
            accI = __builtin_amdgcn_mfma_f32_16x16x32_bf16(aI, bR, accI, 0, 0, 0);
        }
        int q = qt * 16 + l15;
        int b_ = img >> 2, c_ = img & 3;
        int obase = ((b_ ^ 4) * 4 + (c_ ^ 2)) * 128;
#pragma unroll
        for (int r = 0; r < 4; ++r) {
            int p = band * 16 + g4 * 4 + r;
            float re = accR[r], im = accI[r];
            out[((obase + (p ^ 64)) << 7) + (q ^ 64)] = sqrtf(re * re + im * im);
        }
    }
}

extern "C" void kernel_launch(void* const* d_in, const int* in_sizes, int n_in,
                              void* d_out, int out_size, void* d_ws, size_t ws_size,
                              hipStream_t stream) {
    const float* values = (const float*)d_in[0];   // [8,4,32768] f32
    const float* coords = (const float*)d_in[1];   // [32768,2] f32

    char* ws = (char*)d_ws;
    // layout (peak ~10.6 MB):
    unsigned short* Sfrag = (unsigned short*)(ws + 0);          // 192 KB
    unsigned* tileCount   = (unsigned*)(ws + 196608);           // 64 KB  [1024*16] line-padded
    float*    wxy         = (float*)(ws + 262144);              // 1.5 MB [32768*12]
    unsigned* bins        = (unsigned*)(ws + 1835008);          // 768 KB [1024*CAPP]
    unsigned short* Gt    = (unsigned short*)(ws + 2621440);    // 4 MB  [32][256v][256u] bf16
    float*    vt          = (float*)(ws + 6815744);             // 4 MB  [32768][32]

    hipMemsetAsync(tileCount, 0, 1024 * 16 * sizeof(unsigned), stream);

    k_front<<<257, 256, 0, stream>>>(coords, values, Sfrag, wxy, tileCount, bins, vt);
    k_gather_tile<<<1024, 256, 0, stream>>>(wxy, vt, tileCount, bins, Gt);
    k_mmx<<<dim3(8, 32), 512, 0, stream>>>(Gt, Sfrag, (float*)d_out);
}